// Round 8
// baseline (290.340 us; speedup 1.0000x reference)
//
#include <hip/hip_runtime.h>
#include <hip/hip_bf16.h>
#include <stdint.h>

#define HIDDEN 128
#define LDS_STRIDE 136   // shorts per col: 128 + 8 pad (bank-conflict-free ds_read_b128)

typedef __attribute__((ext_vector_type(8))) short short8;
typedef __attribute__((ext_vector_type(4))) unsigned uint4v;
typedef __attribute__((ext_vector_type(4))) float float4v;
typedef __attribute__((ext_vector_type(2))) float float2v;
typedef __attribute__((ext_vector_type(2))) unsigned uint2v;

static __device__ __forceinline__ unsigned short f2bf(float f) {
    union { float f; unsigned u; } v; v.f = f;
    unsigned r = (v.u + 0x7FFFu + ((v.u >> 16) & 1u)) >> 16;
    return (unsigned short)r;
}

// Fast pack: round-half-up (+0x8000) then byte-perm. ±0.5 ULP like RNE.
static __device__ __forceinline__ unsigned pack2bf(float f0, float f1) {
    unsigned u0 = __float_as_uint(f0) + 0x8000u;
    unsigned u1 = __float_as_uint(f1) + 0x8000u;
    return __builtin_amdgcn_perm(u1, u0, 0x07060302u);
}

static __device__ __forceinline__ short8 pack8(float4v lo, float4v hi) {
    uint4v u;
    u[0] = pack2bf(lo[0], lo[1]);
    u[1] = pack2bf(lo[2], lo[3]);
    u[2] = pack2bf(hi[0], hi[1]);
    u[3] = pack2bf(hi[2], hi[3]);
    return *(short8*)&u;
}

// ---------------- prep ----------------
// Wt[j*128+k] = combined W[k][j] (bf16). Permutation within each half:
// physical pp = m*8+tt  <->  logical jj = tt*16+m (b1/W2 permuted to match).
__global__ void prep_wt(const float* __restrict__ W1, const float* __restrict__ b1,
                        const float* __restrict__ W2,
                        unsigned short* __restrict__ Wt,
                        float* __restrict__ b1p, float* __restrict__ W2p) {
    int idx = blockIdx.x * blockDim.x + threadIdx.x;   // 0 .. 32767
    if (idx < 256 * 128) {
        int j = idx >> 7, k = idx & 127;
        float v = (j < 128) ? W1[k * 128 + j] : W1[(128 + k) * 128 + (j - 128)];
        Wt[idx] = f2bf(v);
    }
    if (idx < 128) {
        int m = idx >> 3, tt = idx & 7;
        int jj = tt * 16 + m;
        b1p[idx] = b1[jj];
        W2p[idx] = W2[jj];
    }
}

// ---------------- counting sort of edges by r>>4 ----------------
__global__ void edge_hist(const int* __restrict__ eli, int E, int* __restrict__ cnt) {
    int i = blockIdx.x * 256 + threadIdx.x;
    if (i < E) atomicAdd(&cnt[eli[i] >> 4], 1);
}

__global__ void bucket_scan(int* __restrict__ cnt, int* __restrict__ off, int nb) {
    __shared__ int part[256];
    int t = threadIdx.x;
    int per = (nb + 255) / 256;
    int s = 0;
    for (int i = 0; i < per; ++i) {
        int idx = t * per + i;
        if (idx < nb) s += cnt[idx];
    }
    part[t] = s;
    __syncthreads();
    if (t == 0) {
        int acc = 0;
        for (int i = 0; i < 256; ++i) { int v = part[i]; part[i] = acc; acc += v; }
    }
    __syncthreads();
    int base = part[t];
    for (int i = 0; i < per; ++i) {
        int idx = t * per + i;
        if (idx < nb) { int v = cnt[idx]; off[idx] = base; base += v; }
    }
}

__global__ void edge_scatter(const int* __restrict__ eli, int E, int* __restrict__ cur,
                             int* __restrict__ sr, int* __restrict__ sc,
                             int* __restrict__ se) {
    int i = blockIdx.x * 256 + threadIdx.x;
    if (i < E) {
        int r = eli[i], c = eli[E + i];
        int p = atomicAdd(&cur[r >> 4], 1);
        sr[p] = r; sc[p] = c; se[p] = i;
    }
}

// ---------------- node GEMM (R7 config — LDS-staged, half-specialized) ----------------
__global__ __launch_bounds__(512) void node_gemm(
        const float* __restrict__ z, const unsigned short* __restrict__ Wt,
        const float* __restrict__ b1p,
        unsigned short* __restrict__ Q, int n_nodes) {
    __shared__ unsigned short Wl[128 * LDS_STRIDE];   // 34816 B

    int tid  = threadIdx.x;
    int h    = blockIdx.x & 1;

    #pragma unroll
    for (int i = 0; i < 4; ++i) {
        int chunk = tid + i * 512;                 // 0..2047
        int c  = chunk >> 4;                       // local col 0..127
        int k0 = (chunk & 15) * 8;
        short8 v = *(const short8*)(Wt + h * 16384 + chunk * 8);
        *(short8*)(Wl + c * LDS_STRIDE + k0) = v;
    }
    __syncthreads();

    int lane = tid & 63;
    int wave = tid >> 6;                           // 0..7
    int m    = lane & 15;
    int quad = lane >> 4;

    float4v b1a = (float4v)(0.0f), b1b = (float4v)(0.0f);
    if (h == 0) {
        b1a = *(const float4v*)(b1p + m * 8);
        b1b = *(const float4v*)(b1p + m * 8 + 4);
    }

    int nTiles = (n_nodes + 15) >> 4;
    int tileStride = (gridDim.x >> 1) * 8;

    for (int tile = (blockIdx.x >> 1) * 8 + wave; tile < nTiles; tile += tileStride) {
        int nodebase = tile * 16;
        int row = nodebase + m;

        short8 a[4];
        {
            bool ok = row < n_nodes;
            const float* zp = z + (size_t)row * HIDDEN + quad * 8;
            #pragma unroll
            for (int s = 0; s < 4; ++s) {
                float4v z0 = ok ? *(const float4v*)(zp + s * 32)     : (float4v)(0.0f);
                float4v z1 = ok ? *(const float4v*)(zp + s * 32 + 4) : (float4v)(0.0f);
                a[s] = pack8(z0, z1);
            }
        }

        float4v acc[8];
        #pragma unroll
        for (int t = 0; t < 8; ++t) acc[t] = (float4v)(0.0f);

        #pragma unroll
        for (int t = 0; t < 8; ++t) {
            const unsigned short* wp = Wl + (t * 16 + m) * LDS_STRIDE + quad * 8;
            #pragma unroll
            for (int s = 0; s < 4; ++s) {
                short8 b = *(const short8*)(wp + s * 32);
                acc[t] = __builtin_amdgcn_mfma_f32_16x16x32_bf16(a[s], b, acc[t], 0, 0, 0);
            }
        }

        #pragma unroll
        for (int r = 0; r < 4; ++r) {
            int node = nodebase + quad * 4 + r;
            if (node < n_nodes) {
                uint4v pk;
                pk[0] = pack2bf(acc[0][r] + b1a[0], acc[1][r] + b1a[1]);
                pk[1] = pack2bf(acc[2][r] + b1a[2], acc[3][r] + b1a[3]);
                pk[2] = pack2bf(acc[4][r] + b1b[0], acc[5][r] + b1b[1]);
                pk[3] = pack2bf(acc[6][r] + b1b[2], acc[7][r] + b1b[3]);
                *(uint4v*)(Q + (size_t)node * 256 + h * 128 + m * 8) = pk;
            }
        }
    }
}

// ---------------- edge kernels ----------------
// Shared math: out = sum_pp relu(Q[r][pp] + Q[c][128+pp]) * W2p[pp] + b2 (b1 folded)
static __device__ __forceinline__ float edge_dot(uint4v u1, uint4v u2, const float2v* w) {
    float2v accv = (float2v)(0.0f);
    #pragma unroll
    for (int k = 0; k < 4; ++k) {
        unsigned a1 = u1[k], a2 = u2[k];
        float2v v1, v2;
        v1[0] = __uint_as_float(a1 << 16);
        v1[1] = __uint_as_float(a1 & 0xFFFF0000u);
        v2[0] = __uint_as_float(a2 << 16);
        v2[1] = __uint_as_float(a2 & 0xFFFF0000u);
        float2v s = v1 + v2;
        s[0] = fmaxf(s[0], 0.0f);
        s[1] = fmaxf(s[1], 0.0f);
        accv[0] = fmaf(s[0], w[k][0], accv[0]);
        accv[1] = fmaf(s[1], w[k][1], accv[1]);
    }
    return accv[0] + accv[1];
}

// Sorted path: edges pre-sorted by r>>4 — r-gathers are L1/L2-local.
__global__ __launch_bounds__(256) void edge_kernel_sorted(
        const int* __restrict__ sr, const int* __restrict__ sc,
        const int* __restrict__ se, const unsigned short* __restrict__ Q,
        const float* __restrict__ W2p, const float* __restrict__ b2,
        float* __restrict__ out, int E) {
    int g      = threadIdx.x >> 4;
    int lane16 = threadIdx.x & 15;
    int j0 = lane16 * 8;

    float2v w[4];
    #pragma unroll
    for (int k = 0; k < 4; ++k) w[k] = ((const float2v*)(W2p + j0))[k];
    float bias2 = b2[0];

    int e0 = blockIdx.x * 64 + g;

    int idx_r[4], idx_c[4], oe[4];
    #pragma unroll
    for (int i = 0; i < 4; ++i) {
        int e = e0 + i * 16;
        bool ok = e < E;
        idx_r[i] = ok ? sr[e] : 0;
        idx_c[i] = ok ? sc[e] : 0;
        oe[i]    = ok ? se[e] : 0;
    }

    uint4v u1[4], u2[4];
    #pragma unroll
    for (int i = 0; i < 4; ++i) {
        u1[i] = *(const uint4v*)(Q + (size_t)idx_r[i] * 256 + j0);
        u2[i] = *(const uint4v*)(Q + (size_t)idx_c[i] * 256 + 128 + j0);
    }

    #pragma unroll
    for (int i = 0; i < 4; ++i) {
        float acc = edge_dot(u1[i], u2[i], w);
        acc += __shfl_xor(acc, 1);
        acc += __shfl_xor(acc, 2);
        acc += __shfl_xor(acc, 4);
        acc += __shfl_xor(acc, 8);
        int e = e0 + i * 16;
        if (lane16 == 0 && e < E) out[oe[i]] = acc + bias2;
    }
}

// Fallback (unsorted, R4/R7 plateau config) if ws is too small for sort buffers.
__global__ __launch_bounds__(256) void edge_kernel(
        const int* __restrict__ eli, const unsigned short* __restrict__ Q,
        const float* __restrict__ W2p, const float* __restrict__ b2,
        float* __restrict__ out, int E) {
    int g      = threadIdx.x >> 4;
    int lane16 = threadIdx.x & 15;
    int j0 = lane16 * 8;

    float2v w[4];
    #pragma unroll
    for (int k = 0; k < 4; ++k) w[k] = ((const float2v*)(W2p + j0))[k];
    float bias2 = b2[0];

    int e0 = blockIdx.x * 64 + g;

    int idx_r[4], idx_c[4];
    #pragma unroll
    for (int i = 0; i < 4; ++i) {
        int e = e0 + i * 16;
        idx_r[i] = (e < E) ? eli[e]     : 0;
        idx_c[i] = (e < E) ? eli[E + e] : 0;
    }

    uint4v u1[4], u2[4];
    #pragma unroll
    for (int i = 0; i < 4; ++i) {
        u1[i] = *(const uint4v*)(Q + (size_t)idx_r[i] * 256 + j0);
        u2[i] = *(const uint4v*)(Q + (size_t)idx_c[i] * 256 + 128 + j0);
    }

    #pragma unroll
    for (int i = 0; i < 4; ++i) {
        float acc = edge_dot(u1[i], u2[i], w);
        acc += __shfl_xor(acc, 1);
        acc += __shfl_xor(acc, 2);
        acc += __shfl_xor(acc, 4);
        acc += __shfl_xor(acc, 8);
        int e = e0 + i * 16;
        if (lane16 == 0 && e < E) out[e] = acc + bias2;
    }
}

extern "C" void kernel_launch(void* const* d_in, const int* in_sizes, int n_in,
                              void* d_out, int out_size, void* d_ws, size_t ws_size,
                              hipStream_t stream) {
    const float* z   = (const float*)d_in[0];
    const int*   eli = (const int*)d_in[1];
    const float* W1  = (const float*)d_in[2];
    const float* b1  = (const float*)d_in[3];
    const float* W2  = (const float*)d_in[4];
    const float* b2  = (const float*)d_in[5];
    int n_nodes = in_sizes[0] / HIDDEN;       // 100000
    int E       = in_sizes[1] / 2;            // 1000000
    float* out  = (float*)d_out;

    int nb = (n_nodes + 15) >> 4;             // buckets (r>>4)

    size_t off = 0;
    unsigned short* Q   = (unsigned short*)d_ws;           off += (size_t)n_nodes * 256 * 2;
    unsigned short* Wt  = (unsigned short*)((char*)d_ws + off); off += 256 * 128 * 2;
    float*          b1p = (float*)((char*)d_ws + off);     off += 128 * 4;
    float*          W2p = (float*)((char*)d_ws + off);     off += 128 * 4;
    off = (off + 255) & ~(size_t)255;
    int* sr  = (int*)((char*)d_ws + off);                  off += (size_t)E * 4;
    int* sc  = (int*)((char*)d_ws + off);                  off += (size_t)E * 4;
    int* se  = (int*)((char*)d_ws + off);                  off += (size_t)E * 4;
    int* cnt = (int*)((char*)d_ws + off);                  off += (size_t)nb * 4;
    int* cur = (int*)((char*)d_ws + off);                  off += (size_t)nb * 4;
    bool use_sort = (off <= ws_size);

    prep_wt<<<128, 256, 0, stream>>>(W1, b1, W2, Wt, b1p, W2p);

    if (use_sort) {
        hipMemsetAsync(cnt, 0, (size_t)nb * 4, stream);
        edge_hist<<<(E + 255) / 256, 256, 0, stream>>>(eli, E, cnt);
        bucket_scan<<<1, 256, 0, stream>>>(cnt, cur, nb);
        edge_scatter<<<(E + 255) / 256, 256, 0, stream>>>(eli, E, cur, sr, sc, se);
    }

    node_gemm<<<1024, 512, 0, stream>>>(z, Wt, b1p, Q, n_nodes);

    if (use_sort) {
        edge_kernel_sorted<<<(E + 63) / 64, 256, 0, stream>>>(sr, sc, se, Q, W2p, b2, out, E);
    } else {
        edge_kernel<<<(E + 63) / 64, 256, 0, stream>>>(eli, Q, W2p, b2, out, E);
    }
}

// Round 9
// 162.981 us; speedup vs baseline: 1.7814x; 1.7814x over previous
//
#include <hip/hip_runtime.h>
#include <hip/hip_bf16.h>
#include <stdint.h>

#define HIDDEN 128
#define LDS_STRIDE 136   // shorts per col: 128 + 8 pad (bank-conflict-free ds_read_b128)

typedef __attribute__((ext_vector_type(8))) short short8;
typedef __attribute__((ext_vector_type(4))) unsigned uint4v;
typedef __attribute__((ext_vector_type(4))) float float4v;
typedef __attribute__((ext_vector_type(2))) float float2v;
typedef __attribute__((ext_vector_type(2))) unsigned uint2v;

static __device__ __forceinline__ unsigned short f2bf(float f) {
    union { float f; unsigned u; } v; v.f = f;
    unsigned r = (v.u + 0x7FFFu + ((v.u >> 16) & 1u)) >> 16;
    return (unsigned short)r;
}

// Fast pack f32->bf16 pair: round-half-up (+0x8000) then byte-perm. ±0.5 ULP like RNE.
static __device__ __forceinline__ unsigned pack2bf(float f0, float f1) {
    unsigned u0 = __float_as_uint(f0) + 0x8000u;
    unsigned u1 = __float_as_uint(f1) + 0x8000u;
    return __builtin_amdgcn_perm(u1, u0, 0x07060302u);
}

static __device__ __forceinline__ short8 pack8(float4v lo, float4v hi) {
    uint4v u;
    u[0] = pack2bf(lo[0], lo[1]);
    u[1] = pack2bf(lo[2], lo[3]);
    u[2] = pack2bf(hi[0], hi[1]);
    u[3] = pack2bf(hi[2], hi[3]);
    return *(short8*)&u;
}

// ---------------- prep ----------------
// Wt[j*128+k] = combined W[k][j] (bf16). Permutation within each half:
// physical pp = m*8+tt  <->  logical jj = tt*16+m (b1/W2 permuted to match).
__global__ void prep_wt(const float* __restrict__ W1, const float* __restrict__ b1,
                        const float* __restrict__ W2,
                        unsigned short* __restrict__ Wt,
                        float* __restrict__ b1p, float* __restrict__ W2p) {
    int idx = blockIdx.x * blockDim.x + threadIdx.x;   // 0 .. 32767
    if (idx < 256 * 128) {
        int j = idx >> 7, k = idx & 127;
        float v = (j < 128) ? W1[k * 128 + j] : W1[(128 + k) * 128 + (j - 128)];
        Wt[idx] = f2bf(v);
    }
    if (idx < 128) {
        int m = idx >> 3, tt = idx & 7;
        int jj = tt * 16 + m;
        b1p[idx] = b1[jj];
        W2p[idx] = W2[jj];
    }
}

// ---------------- node GEMM: LDS-staged weights, int8 quantized output ----------------
// Qi[node][h*128 + pp] = biased-uint8 quant of (z@W + b1-fold)[node][half h, phys pp],
// scale per (node, half) in sA/sB: dequant v = s*(q-128).
__global__ __launch_bounds__(512) void node_gemm(
        const float* __restrict__ z, const unsigned short* __restrict__ Wt,
        const float* __restrict__ b1p,
        unsigned char* __restrict__ Qi, float* __restrict__ sA, float* __restrict__ sB,
        int n_nodes) {
    __shared__ unsigned short Wl[128 * LDS_STRIDE];   // 34816 B

    int tid  = threadIdx.x;
    int h    = blockIdx.x & 1;

    #pragma unroll
    for (int i = 0; i < 4; ++i) {
        int chunk = tid + i * 512;                 // 0..2047
        int c  = chunk >> 4;                       // local col 0..127
        int k0 = (chunk & 15) * 8;
        short8 v = *(const short8*)(Wt + h * 16384 + chunk * 8);
        *(short8*)(Wl + c * LDS_STRIDE + k0) = v;
    }
    __syncthreads();

    int lane = tid & 63;
    int wave = tid >> 6;                           // 0..7
    int m    = lane & 15;
    int quad = lane >> 4;

    float4v b1a = (float4v)(0.0f), b1b = (float4v)(0.0f);
    if (h == 0) {
        b1a = *(const float4v*)(b1p + m * 8);
        b1b = *(const float4v*)(b1p + m * 8 + 4);
    }
    float* sArr = (h == 0) ? sA : sB;

    int nTiles = (n_nodes + 15) >> 4;
    int tileStride = (gridDim.x >> 1) * 8;

    for (int tile = (blockIdx.x >> 1) * 8 + wave; tile < nTiles; tile += tileStride) {
        int nodebase = tile * 16;
        int row = nodebase + m;

        short8 a[4];
        {
            bool ok = row < n_nodes;
            const float* zp = z + (size_t)row * HIDDEN + quad * 8;
            #pragma unroll
            for (int s = 0; s < 4; ++s) {
                float4v z0 = ok ? *(const float4v*)(zp + s * 32)     : (float4v)(0.0f);
                float4v z1 = ok ? *(const float4v*)(zp + s * 32 + 4) : (float4v)(0.0f);
                a[s] = pack8(z0, z1);
            }
        }

        float4v acc[8];
        #pragma unroll
        for (int t = 0; t < 8; ++t) acc[t] = (float4v)(0.0f);

        #pragma unroll
        for (int t = 0; t < 8; ++t) {
            const unsigned short* wp = Wl + (t * 16 + m) * LDS_STRIDE + quad * 8;
            #pragma unroll
            for (int s = 0; s < 4; ++s) {
                short8 b = *(const short8*)(wp + s * 32);
                acc[t] = __builtin_amdgcn_mfma_f32_16x16x32_bf16(a[s], b, acc[t], 0, 0, 0);
            }
        }

        // Epilogue: per node (quad,r): bias-fold, 16-lane row-max, int8 quantize.
        #pragma unroll
        for (int r = 0; r < 4; ++r) {
            int node = nodebase + quad * 4 + r;
            float v[8];
            v[0] = acc[0][r] + b1a[0]; v[1] = acc[1][r] + b1a[1];
            v[2] = acc[2][r] + b1a[2]; v[3] = acc[3][r] + b1a[3];
            v[4] = acc[4][r] + b1b[0]; v[5] = acc[5][r] + b1b[1];
            v[6] = acc[6][r] + b1b[2]; v[7] = acc[7][r] + b1b[3];

            float amax = fabsf(v[0]);
            #pragma unroll
            for (int t = 1; t < 8; ++t) amax = fmaxf(amax, fabsf(v[t]));
            // max across the 16 lanes (same quad) holding this node's 128 cols
            amax = fmaxf(amax, __shfl_xor(amax, 1));
            amax = fmaxf(amax, __shfl_xor(amax, 2));
            amax = fmaxf(amax, __shfl_xor(amax, 4));
            amax = fmaxf(amax, __shfl_xor(amax, 8));
            amax = fmaxf(amax, 1e-30f);

            float inv = 126.5f * __builtin_amdgcn_rcpf(amax);
            float s   = amax * (1.0f / 126.5f);

            unsigned d0 = 0, d1 = 0;
            #pragma unroll
            for (int t = 0; t < 4; ++t) {
                int q = (int)rintf(fmaf(v[t], inv, 128.0f));
                d0 |= ((unsigned)q & 255u) << (8 * t);
            }
            #pragma unroll
            for (int t = 0; t < 4; ++t) {
                int q = (int)rintf(fmaf(v[4 + t], inv, 128.0f));
                d1 |= ((unsigned)q & 255u) << (8 * t);
            }

            if (node < n_nodes) {
                uint2v pk; pk[0] = d0; pk[1] = d1;
                *(uint2v*)(Qi + (size_t)node * 256 + h * 128 + m * 8) = pk;
                if (m == 0) sArr[node] = s;
            }
        }
    }
}

// ---------------- edge kernel: int8 gathers, half traffic ----------------
// out[e] = sum_pp relu(sA[r]*(a-128) + sB[c]*(b-128)) * W2p[pp] + b2  (b1 pre-folded)
// 16 lanes per edge, 4 edges per group (measured plateau config).
__global__ __launch_bounds__(256) void edge_kernel(
        const int* __restrict__ eli, const unsigned char* __restrict__ Qi,
        const float* __restrict__ sA, const float* __restrict__ sB,
        const float* __restrict__ W2p, const float* __restrict__ b2,
        float* __restrict__ out, int E) {
    int g      = threadIdx.x >> 4;
    int lane16 = threadIdx.x & 15;
    int j0 = lane16 * 8;

    float4v wA = *(const float4v*)(W2p + j0);
    float4v wB = *(const float4v*)(W2p + j0 + 4);
    float bias2 = b2[0];

    int e0 = blockIdx.x * 64 + g;

    int idx_r[4], idx_c[4];
    #pragma unroll
    for (int i = 0; i < 4; ++i) {
        int e = e0 + i * 16;
        idx_r[i] = (e < E) ? eli[e]     : 0;
        idx_c[i] = (e < E) ? eli[E + e] : 0;
    }

    uint2v u1[4], u2[4];
    float s1[4], s2[4];
    #pragma unroll
    for (int i = 0; i < 4; ++i) {
        u1[i] = *(const uint2v*)(Qi + (size_t)idx_r[i] * 256 + j0);
        u2[i] = *(const uint2v*)(Qi + (size_t)idx_c[i] * 256 + 128 + j0);
        s1[i] = sA[idx_r[i]];
        s2[i] = sB[idx_c[i]];
    }

    #pragma unroll
    for (int i = 0; i < 4; ++i) {
        float a1 = s1[i], a2 = s2[i];
        float off = -128.0f * (a1 + a2);
        float acc = 0.0f;
        unsigned da = u1[i][0], db = u2[i][0];
        #pragma unroll
        for (int k = 0; k < 4; ++k) {
            float af = (float)((da >> (8 * k)) & 255u);
            float bf = (float)((db >> (8 * k)) & 255u);
            float v = fmaf(a2, bf, fmaf(a1, af, off));
            v = fmaxf(v, 0.0f);
            acc = fmaf(v, wA[k], acc);
        }
        da = u1[i][1]; db = u2[i][1];
        #pragma unroll
        for (int k = 0; k < 4; ++k) {
            float af = (float)((da >> (8 * k)) & 255u);
            float bf = (float)((db >> (8 * k)) & 255u);
            float v = fmaf(a2, bf, fmaf(a1, af, off));
            v = fmaxf(v, 0.0f);
            acc = fmaf(v, wB[k], acc);
        }

        acc += __shfl_xor(acc, 1);
        acc += __shfl_xor(acc, 2);
        acc += __shfl_xor(acc, 4);
        acc += __shfl_xor(acc, 8);

        int e = e0 + i * 16;
        if (lane16 == 0 && e < E) out[e] = acc + bias2;
    }
}

extern "C" void kernel_launch(void* const* d_in, const int* in_sizes, int n_in,
                              void* d_out, int out_size, void* d_ws, size_t ws_size,
                              hipStream_t stream) {
    const float* z   = (const float*)d_in[0];
    const int*   eli = (const int*)d_in[1];
    const float* W1  = (const float*)d_in[2];
    const float* b1  = (const float*)d_in[3];
    const float* W2  = (const float*)d_in[4];
    const float* b2  = (const float*)d_in[5];
    int n_nodes = in_sizes[0] / HIDDEN;       // 100000
    int E       = in_sizes[1] / 2;            // 1000000
    float* out  = (float*)d_out;

    size_t off = 0;
    unsigned char* Qi  = (unsigned char*)d_ws;              off += (size_t)n_nodes * 256;
    unsigned short* Wt = (unsigned short*)((char*)d_ws + off); off += 256 * 128 * 2;
    float* b1p = (float*)((char*)d_ws + off);               off += 128 * 4;
    float* W2p = (float*)((char*)d_ws + off);               off += 128 * 4;
    float* sA  = (float*)((char*)d_ws + off);               off += (size_t)n_nodes * 4;
    float* sB  = (float*)((char*)d_ws + off);               off += (size_t)n_nodes * 4;

    prep_wt<<<128, 256, 0, stream>>>(W1, b1, W2, Wt, b1p, W2p);

    node_gemm<<<1024, 512, 0, stream>>>(z, Wt, b1p, Qi, sA, sB, n_nodes);

    edge_kernel<<<(E + 63) / 64, 256, 0, stream>>>(eli, Qi, sA, sB, W2p, b2, out, E);
}